// Round 23
// baseline (105.954 us; speedup 1.0000x reference)
//
#include <hip/hip_runtime.h>
#include <hip/hip_bf16.h>
#include <math.h>

// CausalFullAttention: out[b,l,h,d] = softmax_s( 0.125*(q.k + bias[l,s]), s<=l ) @ V
// B=4 L=S=2048 H=8 E=D=64, fp32 in/out, bf16 MFMA compute.
// R22: ZERO barriers. 1-wave (64-thr) blocks, private dbuf LDS (16KB) -> 10
//      independent wave-streams/CU. KV tile 32; rho32 K-perm makes QK^T C-layout
//      == PV A-layout (direct pack); per-wave counted vmcnt(10) staging discipline
//      (never drain mid-loop). prep/merge/ws identical to passing R21.

typedef __bf16 bf16x8 __attribute__((ext_vector_type(8)));
typedef float  f32x4  __attribute__((ext_vector_type(4)));
typedef unsigned int u32;
typedef unsigned short u16;
typedef u32 u32x4 __attribute__((ext_vector_type(4)));

#define NB 4
#define NL 2048
#define NS 2048
#define NH 8
#define NE 64
#define ND 64

// ws layout (floats)
#define KBF_F 0
#define VT_F  2097152
#define OP_F  4194304
#define M_F   8388608
#define L_F   8454144
#define WS_NEED_F 8519680          // 34,078,720 bytes

typedef __attribute__((address_space(3))) u32 lds_u32;
typedef __attribute__((address_space(1))) const u32 glb_u32;
__device__ __forceinline__ void gload16(const void* g, void* l) {
    __builtin_amdgcn_global_load_lds((glb_u32*)g, (lds_u32*)l, 16, 0, 0);
}

__device__ __forceinline__ u32 cvtpk(float lo, float hi) {
    u32 r;
    asm("v_cvt_pk_bf16_f32 %0, %1, %2" : "=v"(r) : "v"(lo), "v"(hi));
    return r;
}
__device__ __forceinline__ float bpermf(int srclane, float v) {
    return __uint_as_float((u32)__builtin_amdgcn_ds_bpermute(srclane << 2, (int)__float_as_uint(v)));
}
__device__ __forceinline__ bf16x8 cvt8s(f32x4 a, f32x4 b, float sc) {
    bf16x8 r;
    r[0]=(__bf16)(a[0]*sc); r[1]=(__bf16)(a[1]*sc); r[2]=(__bf16)(a[2]*sc); r[3]=(__bf16)(a[3]*sc);
    r[4]=(__bf16)(b[0]*sc); r[5]=(__bf16)(b[1]*sc); r[6]=(__bf16)(b[2]*sc); r[7]=(__bf16)(b[3]*sc);
    return r;
}
__device__ __forceinline__ bf16x8 cvt8(f32x4 a, f32x4 b) {
    bf16x8 r;
    r[0]=(__bf16)a[0]; r[1]=(__bf16)a[1]; r[2]=(__bf16)a[2]; r[3]=(__bf16)a[3];
    r[4]=(__bf16)b[0]; r[5]=(__bf16)b[1]; r[6]=(__bf16)b[2]; r[7]=(__bf16)b[3];
    return r;
}

// -------- fused pre-pass: blocks [0,2048) convert K; [2048,3072) transpose V -----
__global__ __launch_bounds__(256)
void prep(const float* __restrict__ K, const float* __restrict__ V,
          u16* __restrict__ Kbf, u16* __restrict__ Vt)
{
    __shared__ __bf16 T[64][72];
    const int bid = blockIdx.x;
    const int t   = threadIdx.x;
    if (bid < 2048) {
        const int i = (bid * 256 + t) * 8;
        f32x4 a = *(const f32x4*)(K + i);
        f32x4 b = *(const f32x4*)(K + i + 4);
        *(bf16x8*)(Kbf + i) = cvt8(a, b);
    } else {
        const int id = bid - 2048;
        const int bh = id >> 5, sblk = (id & 31) << 6;
        const int b = bh >> 3, h = bh & 7;
        {
            const int sl = t >> 2, d0 = (t & 3) << 4;
            const float* vp = V + (((size_t)(b * NS + sblk + sl)) * NH + h) * ND + d0;
            f32x4 a0 = ((const f32x4*)vp)[0], a1 = ((const f32x4*)vp)[1];
            f32x4 a2 = ((const f32x4*)vp)[2], a3 = ((const f32x4*)vp)[3];
            *(bf16x8*)&T[sl][d0]     = cvt8(a0, a1);
            *(bf16x8*)&T[sl][d0 + 8] = cvt8(a2, a3);
        }
        __syncthreads();
        {
            const int dl = t >> 2, s0 = (t & 3) << 4;
            bf16x8 o0, o1;
            #pragma unroll
            for (int k = 0; k < 8; ++k) { o0[k] = T[s0 + k][dl]; o1[k] = T[s0 + 8 + k][dl]; }
            u16* op = Vt + (((size_t)(b * NH + h)) * ND + dl) * NS + sblk + s0;
            *(bf16x8*)op       = o0;
            *(bf16x8*)(op + 8) = o1;
        }
    }
}

// ---- core: ONE wave, 16 q-rows, 32-kv tiles [T0,T1), zero barriers ----
__device__ __forceinline__ void fa_core(const float* __restrict__ Q,
                                        const u16* __restrict__ Kbf,
                                        const u16* __restrict__ Vt,
                                        const float* __restrict__ Bias,
                                        float* __restrict__ OutOrO,
                                        float* __restrict__ Mp, float* __restrict__ Lp,
                                        int b, int h, int qw, int T0, int T1,
                                        bool write_ws,
                                        __bf16 (*Klin)[2048], __bf16 (*Vlin)[2048])
{
    const int lane = threadIdx.x & 63;
    const int g    = lane >> 4, li = lane & 15;

    const float SC = 0.125f * 1.44269504088896340736f;

    bf16x8 qa[2];
    {
        const float* qp = Q + (((size_t)(b * NL + qw + li)) * NH + h) * NE;
        #pragma unroll
        for (int eh = 0; eh < 2; ++eh) {
            const int e0 = eh * 32 + g * 8;
            f32x4 f0 = *(const f32x4*)(qp + e0);
            f32x4 f1 = *(const f32x4*)(qp + e0 + 4);
            qa[eh] = cvt8s(f0, f1, SC);
        }
    }

    f32x4 o[4] = {};
    float m_run = -INFINITY, l_part = 0.0f;

    // per-lane gload source geometry: 4 K + 4 V issues per tile
    // K: LDS [32 rows][64 bf16], row = rho32(kv) = kv2*16 + kv43*4 + kv10,
    //    slot j holds e-chunk (j ^ (row&7)).
    const u16* kg[4];
    const u16* vg[4];
    #pragma unroll
    for (int n = 0; n < 4; ++n) {
        const int byte = n * 1024 + lane * 16;
        const int rk = byte >> 7, jk = (byte >> 4) & 7;
        const int kv = ((rk >> 2) & 3) * 8 + ((rk >> 4) & 1) * 4 + (rk & 3);
        kg[n] = Kbf + ((size_t)(b * NS + kv) * NH + h) * NE + (jk ^ (rk & 7)) * 8;
        const int dv = byte >> 6, jv = (byte >> 4) & 3;
        const int sdv = (dv ^ (dv >> 2)) & 3;
        vg[n] = Vt + ((size_t)(b * NH + h) * ND + dv) * NS + (jv ^ sdv) * 8;
    }

    const float* bp0 = Bias + (size_t)(qw + li) * NS + g * 8;

    f32x4 bc[2], bn[2];

    auto stage = [&](int buf, int T) {
        const size_t kq = (size_t)(T << 5) * (NH * NE);
        const int    vq = T << 5;
        #pragma unroll
        for (int n = 0; n < 4; ++n) gload16(kg[n] + kq, &Klin[buf][n * 512]);
        #pragma unroll
        for (int n = 0; n < 4; ++n) gload16(vg[n] + vq, &Vlin[buf][n * 512]);
    };
    auto load_bias = [&](f32x4 (&bx)[2], int T) {
        const float* bp = bp0 + (T << 5);
        bx[0] = *(const f32x4*)(bp);
        bx[1] = *(const f32x4*)(bp + 4);
    };

    const int nt = T1 - T0;

    // prologue: tile T0 in flight
    load_bias(bc, T0);
    stage(0, T0);

    for (int i = 0; i < nt; ++i) {
        const int t = T0 + i;
        const int cur = i & 1;
        const bool more = (i + 1 < nt);

        if (more) { load_bias(bn, t + 1); stage(cur ^ 1, t + 1); }

        // wave-local counted wait: tile t's 8 gloads done; t+1's (8+2) stay in flight
        if (more) asm volatile("s_waitcnt vmcnt(10)" ::: "memory");
        else      asm volatile("s_waitcnt vmcnt(0)"  ::: "memory");
        __builtin_amdgcn_sched_barrier(0);

        const int kv0 = t << 5;
        // swapped QK^T on rho32-permuted K: s[c][r] = S[kv0 + g*8 + c*4 + r][q=qw+li]
        f32x4 s[2];
        __builtin_amdgcn_s_setprio(1);
        #pragma unroll
        for (int c = 0; c < 2; ++c) {
            f32x4 acc = {};
            #pragma unroll
            for (int eh = 0; eh < 2; ++eh) {
                bf16x8 kb = *(const bf16x8*)&Klin[cur][(c * 16 + li) * 64 + (((eh * 4 + g) ^ (li & 7)) * 8)];
                acc = __builtin_amdgcn_mfma_f32_16x16x32_bf16(kb, qa[eh], acc, 0, 0, 0);
            }
            s[c] = acc;
        }
        __builtin_amdgcn_s_setprio(0);
        const int lg = qw + li;
        if (kv0 + 31 > qw) {              // straddle: bias + causal select
            #pragma unroll
            for (int c = 0; c < 2; ++c) {
                const int kvb = kv0 + (g << 3) + (c << 2);
                #pragma unroll
                for (int r = 0; r < 4; ++r)
                    s[c][r] = (kvb + r <= lg) ? fmaf(bc[c][r], SC, s[c][r]) : -INFINITY;
            }
        } else {
            #pragma unroll
            for (int c = 0; c < 2; ++c)
                #pragma unroll
                for (int r = 0; r < 4; ++r)
                    s[c][r] = fmaf(bc[c][r], SC, s[c][r]);
        }
        // row max: 7 in-lane + 2 shuffles
        float pm = fmaxf(
            fmaxf(fmaxf(s[0][0], s[0][1]), fmaxf(s[0][2], s[0][3])),
            fmaxf(fmaxf(s[1][0], s[1][1]), fmaxf(s[1][2], s[1][3])));
        pm = fmaxf(pm, __shfl_xor(pm, 16, 64));
        pm = fmaxf(pm, __shfl_xor(pm, 32, 64));
        if (!__all(pm <= m_run + 8.0f)) {     // defer-max (T13)
            const float mn = fmaxf(m_run, pm);
            const float corr = exp2f(m_run - mn);
            m_run = mn; l_part *= corr;
            #pragma unroll
            for (int j = 0; j < 4; ++j) {
                const float cj = bpermf(g * 20 + j, corr);
                o[0][j] *= cj; o[1][j] *= cj; o[2][j] *= cj; o[3][j] *= cj;
            }
        }
        #pragma unroll
        for (int c = 0; c < 2; ++c)
            #pragma unroll
            for (int r = 0; r < 4; ++r)
                s[c][r] = exp2f(s[c][r] - m_run);
        // per-lane partial sum only (cross-lane reduce deferred to epilogue)
        l_part += ((s[0][0] + s[0][1]) + (s[0][2] + s[0][3]))
                + ((s[1][0] + s[1][1]) + (s[1][2] + s[1][3]));
        // P -> PV A-frag: direct pack (rho32 aligned kv order)
        u32x4 pw;
        pw[0] = cvtpk(s[0][0], s[0][1]); pw[1] = cvtpk(s[0][2], s[0][3]);
        pw[2] = cvtpk(s[1][0], s[1][1]); pw[3] = cvtpk(s[1][2], s[1][3]);
        const bf16x8 pa = __builtin_bit_cast(bf16x8, pw);
        __builtin_amdgcn_s_setprio(1);
        #pragma unroll
        for (int dt = 0; dt < 4; ++dt) {
            const int d = dt * 16 + li;
            const int sdv = (d ^ (d >> 2)) & 3;
            bf16x8 v = *(const bf16x8*)&Vlin[cur][d * 32 + ((g ^ sdv) * 8)];
            o[dt] = __builtin_amdgcn_mfma_f32_16x16x32_bf16(pa, v, o[dt], 0, 0, 0);
        }
        __builtin_amdgcn_s_setprio(0);

        if (more) { bc[0] = bn[0]; bc[1] = bn[1]; }
    }

    // epilogue: finish l reduction, then store
    float l_run = l_part;
    l_run += __shfl_xor(l_run, 16, 64);
    l_run += __shfl_xor(l_run, 32, 64);

    if (write_ws) {
        #pragma unroll
        for (int j = 0; j < 4; ++j) {
            const int lp = qw + g * 4 + j - 1024;
            float* op = OutOrO + (((size_t)(b * 1024 + lp)) * NH + h) * ND + li;
            op[0]  = o[0][j];
            op[16] = o[1][j];
            op[32] = o[2][j];
            op[48] = o[3][j];
        }
        if (g == 0) {
            const size_t rh = ((size_t)(b * 1024 + qw + li - 1024)) * NH + h;
            Mp[rh] = m_run;
            Lp[rh] = l_run;
        }
    } else {
        #pragma unroll
        for (int j = 0; j < 4; ++j) {
            const float lj = bpermf(g * 20 + j, l_run);
            const float inv = 1.0f / lj;
            const int lgq = qw + g * 4 + j;
            float* op = OutOrO + (((size_t)(b * NL + lgq)) * NH + h) * ND + li;
            op[0]  = o[0][j] * inv;
            op[16] = o[1][j] * inv;
            op[32] = o[2][j] * inv;
            op[48] = o[3][j] * inv;
        }
    }
}

// ---- split kernel: 6144 one-wave blocks = 48 segs x 32 bh x 4 waves ----
__global__ __launch_bounds__(64)
void fa_part(const float* __restrict__ Q, const float* __restrict__ Bias,
             float* __restrict__ Ws, float* __restrict__ Out)
{
    __shared__ __bf16 Klin[2][2048];
    __shared__ __bf16 Vlin[2][2048];

    const int id = blockIdx.x;
    const int w  = id & 3;
    const int bh = (id >> 2) & 31;
    const int k  = id >> 7;
    const int b  = bh >> 3, h = bh & 7;
    int qc, s;
    if (k < 16)      { qc = 31 - k;        s = 0; }
    else if (k < 32) { qc = 31 - (k - 16); s = 1; }
    else             { qc = 47 - k;        s = 0; }
    const int qw = (qc << 6) + (w << 4);
    const int lt = (qw + 15) >> 5;                       // last causal 32-tile
    const int T0 = s ? 32 : 0;
    const int T1b = s ? (2 * qc + 2) : min(32, 2 * qc + 2);
    const int T1 = min(T1b, lt + 1);

    const u16* Kbf = (const u16*)(Ws + KBF_F);
    const u16* Vt  = (const u16*)(Ws + VT_F);
    if (qc >= 16) {
        float* Op = Ws + OP_F + (size_t)s * 2097152;
        float* Mp = Ws + M_F + (size_t)s * 32768;
        float* Lp = Ws + L_F + (size_t)s * 32768;
        fa_core(Q, Kbf, Vt, Bias, Op, Mp, Lp, b, h, qw, T0, T1, true, Klin, Vlin);
    } else {
        fa_core(Q, Kbf, Vt, Bias, Out, nullptr, nullptr, b, h, qw, T0, T1, false, Klin, Vlin);
    }
}

// ---- merge kernel: rows l in [1024,2048) only (always exactly 2 segments) ----
__global__ __launch_bounds__(256)
void fa_merge(const float* __restrict__ Ws, float* __restrict__ Out)
{
    const int gid  = blockIdx.x * 256 + threadIdx.x;
    const int base = gid << 2;
    const int rh   = base >> 6;
    const int d0   = base & 63;
    const float* O1 = Ws + OP_F;
    const float* O2 = Ws + OP_F + 2097152;
    const float m1 = Ws[M_F + rh],         l1 = Ws[L_F + rh];
    const float m2 = Ws[M_F + 32768 + rh], l2 = Ws[L_F + 32768 + rh];
    const float mm = fmaxf(m1, m2);
    const float c1 = exp2f(m1 - mm), c2 = exp2f(m2 - mm);
    const float inv = 1.0f / (c1 * l1 + c2 * l2);
    const f32x4 o1 = *(const f32x4*)(O1 + base);
    const f32x4 o2 = *(const f32x4*)(O2 + base);
    f32x4 r;
    #pragma unroll
    for (int e = 0; e < 4; ++e) r[e] = (c1 * o1[e] + c2 * o2[e]) * inv;
    const int h  = rh & 7;
    const int bl = rh >> 3;
    const int lp = bl & 1023, b = bl >> 10;
    float* op = Out + (((size_t)(b * NL + 1024 + lp)) * NH + h) * ND + d0;
    *(f32x4*)op = r;
}

// ---- fallback (ws only fits Kbf+Vt): 1-wave blocks, full causal ranges ----
__global__ __launch_bounds__(64)
void fa_single(const float* __restrict__ Q, const float* __restrict__ Bias,
               float* __restrict__ Ws, float* __restrict__ Out)
{
    __shared__ __bf16 Klin[2][2048];
    __shared__ __bf16 Vlin[2][2048];
    const int id = blockIdx.x;
    const int w  = id & 3;
    const int bh = (id >> 2) & 31;
    const int qc = 31 - (id >> 7);
    const int b  = bh >> 3, h = bh & 7;
    const int qw = (qc << 6) + (w << 4);
    const int lt = (qw + 15) >> 5;
    const int T1 = min(2 * qc + 2, lt + 1);
    const u16* Kbf = (const u16*)(Ws + KBF_F);
    const u16* Vt  = (const u16*)(Ws + VT_F);
    fa_core(Q, Kbf, Vt, Bias, Out, nullptr, nullptr, b, h, qw, 0, T1, false, Klin, Vlin);
}

extern "C" void kernel_launch(void* const* d_in, const int* in_sizes, int n_in,
                              void* d_out, int out_size, void* d_ws, size_t ws_size,
                              hipStream_t stream)
{
    const float* Q    = (const float*)d_in[0];
    const float* K    = (const float*)d_in[1];
    const float* V    = (const float*)d_in[2];
    const float* Bias = (const float*)d_in[3];
    float* Out = (float*)d_out;
    float* Ws  = (float*)d_ws;

    prep<<<dim3(3072), dim3(256), 0, stream>>>(K, V, (u16*)(Ws + KBF_F), (u16*)(Ws + VT_F));

    if (ws_size >= (size_t)WS_NEED_F * sizeof(float)) {
        fa_part <<<dim3(6144), dim3(64), 0, stream>>>(Q, Bias, Ws, Out);
        fa_merge<<<dim3(2048), dim3(256), 0, stream>>>(Ws, Out);
    } else {
        fa_single<<<dim3(4096), dim3(64), 0, stream>>>(Q, Bias, Ws, Out);
    }
}

// Round 24
// 85.126 us; speedup vs baseline: 1.2447x; 1.2447x over previous
//
#include <hip/hip_runtime.h>
#include <hip/hip_bf16.h>
#include <math.h>

// CausalFullAttention: out[b,l,h,d] = softmax_s( 0.125*(q.k + bias[l,s]), s<=l ) @ V
// B=4 L=S=2048 H=8 E=D=64, fp32 in/out, bf16 MFMA compute.
// R23: consolidation. R21 core (gload_lds staging, K row-perm + XOR swizzles,
//      4-wave blocks) with split restricted to qc>=24 (tail <=16 tiles); qc<=23
//      runs unsplit with direct final write. Merge covers only l in [1536,2048).
//      1280 part blocks, heavy-first. prep/ws layout unchanged.

typedef __bf16 bf16x8 __attribute__((ext_vector_type(8)));
typedef float  f32x4  __attribute__((ext_vector_type(4)));
typedef unsigned int u32;
typedef unsigned short u16;
typedef u32 u32x4 __attribute__((ext_vector_type(4)));

#define NB 4
#define NL 2048
#define NS 2048
#define NH 8
#define NE 64
#define ND 64

// ws layout (floats)
#define KBF_F 0
#define VT_F  2097152
#define OP_F  4194304
#define M_F   8388608
#define L_F   8454144
#define WS_NEED_F 8519680          // 34,078,720 bytes

typedef __attribute__((address_space(3))) u32 lds_u32;
typedef __attribute__((address_space(1))) const u32 glb_u32;
__device__ __forceinline__ void gload16(const void* g, void* l) {
    __builtin_amdgcn_global_load_lds((glb_u32*)g, (lds_u32*)l, 16, 0, 0);
}

__device__ __forceinline__ u32 cvtpk(float lo, float hi) {
    u32 r;
    asm("v_cvt_pk_bf16_f32 %0, %1, %2" : "=v"(r) : "v"(lo), "v"(hi));
    return r;
}
__device__ __forceinline__ float bpermf(int srclane, float v) {
    return __uint_as_float((u32)__builtin_amdgcn_ds_bpermute(srclane << 2, (int)__float_as_uint(v)));
}
__device__ __forceinline__ bf16x8 cvt8s(f32x4 a, f32x4 b, float sc) {
    bf16x8 r;
    r[0]=(__bf16)(a[0]*sc); r[1]=(__bf16)(a[1]*sc); r[2]=(__bf16)(a[2]*sc); r[3]=(__bf16)(a[3]*sc);
    r[4]=(__bf16)(b[0]*sc); r[5]=(__bf16)(b[1]*sc); r[6]=(__bf16)(b[2]*sc); r[7]=(__bf16)(b[3]*sc);
    return r;
}
__device__ __forceinline__ bf16x8 cvt8(f32x4 a, f32x4 b) {
    bf16x8 r;
    r[0]=(__bf16)a[0]; r[1]=(__bf16)a[1]; r[2]=(__bf16)a[2]; r[3]=(__bf16)a[3];
    r[4]=(__bf16)b[0]; r[5]=(__bf16)b[1]; r[6]=(__bf16)b[2]; r[7]=(__bf16)b[3];
    return r;
}

// -------- fused pre-pass: blocks [0,2048) convert K; [2048,3072) transpose V -----
__global__ __launch_bounds__(256)
void prep(const float* __restrict__ K, const float* __restrict__ V,
          u16* __restrict__ Kbf, u16* __restrict__ Vt)
{
    __shared__ __bf16 T[64][72];
    const int bid = blockIdx.x;
    const int t   = threadIdx.x;
    if (bid < 2048) {
        const int i = (bid * 256 + t) * 8;
        f32x4 a = *(const f32x4*)(K + i);
        f32x4 b = *(const f32x4*)(K + i + 4);
        *(bf16x8*)(Kbf + i) = cvt8(a, b);
    } else {
        const int id = bid - 2048;
        const int bh = id >> 5, sblk = (id & 31) << 6;
        const int b = bh >> 3, h = bh & 7;
        {
            const int sl = t >> 2, d0 = (t & 3) << 4;
            const float* vp = V + (((size_t)(b * NS + sblk + sl)) * NH + h) * ND + d0;
            f32x4 a0 = ((const f32x4*)vp)[0], a1 = ((const f32x4*)vp)[1];
            f32x4 a2 = ((const f32x4*)vp)[2], a3 = ((const f32x4*)vp)[3];
            *(bf16x8*)&T[sl][d0]     = cvt8(a0, a1);
            *(bf16x8*)&T[sl][d0 + 8] = cvt8(a2, a3);
        }
        __syncthreads();
        {
            const int dl = t >> 2, s0 = (t & 3) << 4;
            bf16x8 o0, o1;
            #pragma unroll
            for (int k = 0; k < 8; ++k) { o0[k] = T[s0 + k][dl]; o1[k] = T[s0 + 8 + k][dl]; }
            u16* op = Vt + (((size_t)(b * NH + h)) * ND + dl) * NS + sblk + s0;
            *(bf16x8*)op       = o0;
            *(bf16x8*)(op + 8) = o1;
        }
    }
}

// ---- core: 256 threads, 4 waves x 16 q-rows, tiles [t0,t1); gload_lds staging ----
template<bool WRITE_WS>
__device__ __forceinline__ void fa_core(const float* __restrict__ Q,
                                        const u16* __restrict__ Kbf,
                                        const u16* __restrict__ Vt,
                                        const float* __restrict__ Bias,
                                        float* __restrict__ OutOrO,
                                        float* __restrict__ Mp, float* __restrict__ Lp,
                                        int b, int h, int qb, int t0, int t1,
                                        __bf16 (*Klin)[4096], __bf16 (*Vlin)[4096])
{
    const int tid  = threadIdx.x;
    const int w    = tid >> 6, lane = tid & 63;
    const int g    = lane >> 4, li = lane & 15;
    const int qw   = qb + (w << 4);

    const float SC = 0.125f * 1.44269504088896340736f;

    bf16x8 qa[2];
    {
        const float* qp = Q + (((size_t)(b * NL + qw + li)) * NH + h) * NE;
        #pragma unroll
        for (int eh = 0; eh < 2; ++eh) {
            const int e0 = eh * 32 + g * 8;
            f32x4 f0 = *(const f32x4*)(qp + e0);
            f32x4 f1 = *(const f32x4*)(qp + e0 + 4);
            qa[eh] = cvt8s(f0, f1, SC);
        }
    }

    f32x4 o[4] = {};
    float m_run = -INFINITY, l_run = 0.0f;

    const int nt = t1 - t0;

    // per-lane gload source geometry (2 K issues + 2 V issues per thread)
    const int ob0 = w * 2048 + lane * 16;            // LDS byte offset, issue 0
    const int r0  = ob0 >> 7,          j0 = (ob0 >> 4) & 7;
    const int r1  = (ob0 + 1024) >> 7, j1 = ((ob0 + 1024) >> 4) & 7;
    // rho^-1: kv2=r4, kv4:3=r3:2, rest pass-through
    const int kv0i = (r0 & 0x23) | ((r0 & 0x10) >> 2) | ((r0 & 0x0C) << 1);
    const int kv1i = (r1 & 0x23) | ((r1 & 0x10) >> 2) | ((r1 & 0x0C) << 1);
    const u16* kgp0 = Kbf + ((size_t)(b * NS + kv0i) * NH + h) * NE + (j0 ^ (r0 & 7)) * 8;
    const u16* kgp1 = Kbf + ((size_t)(b * NS + kv1i) * NH + h) * NE + (j1 ^ (r1 & 7)) * 8;
    const int sd0 = (r0 ^ (r0 >> 3)) & 7, sd1 = (r1 ^ (r1 >> 3)) & 7;
    const u16* vgp0 = Vt + ((size_t)(b * NH + h) * ND + r0) * NS + (j0 ^ sd0) * 8;
    const u16* vgp1 = Vt + ((size_t)(b * NH + h) * ND + r1) * NS + (j1 ^ sd1) * 8;

    const float* bp0 = Bias + (size_t)(qw + li) * NS + g * 8;

    f32x4 bc[4], bn[4];

    auto stage = [&](int buf, int T) {
        const size_t kq = (size_t)(T << 6) * (NH * NE);
        const int    vq = T << 6;
        gload16(kgp0 + kq, &Klin[buf][w * 1024]);
        gload16(kgp1 + kq, &Klin[buf][w * 1024 + 512]);
        gload16(vgp0 + vq, &Vlin[buf][w * 1024]);
        gload16(vgp1 + vq, &Vlin[buf][w * 1024 + 512]);
    };
    auto load_bias = [&](f32x4 (&bx)[4], int T) {
        const float* bp = bp0 + (T << 6);
        #pragma unroll
        for (int c = 0; c < 4; ++c)
            bx[c] = *(const f32x4*)(bp + ((c >> 1) << 5) + ((c & 1) << 2));
    };

    // prologue
    stage(0, t0);
    load_bias(bc, t0);
    __syncthreads();

    for (int i = 0; i < nt; ++i) {
        const int t = t0 + i;
        const int cur = i & 1;
        const bool more = (i + 1 < nt);

        if (more) { stage(cur ^ 1, t + 1); load_bias(bn, t + 1); }

        const int kv0 = t << 6;
        if (kv0 <= qw + 15) {
            // swapped QK^T: s[c][r] = S[kv=kv0+32(c>>1)+8g+4(c&1)+r][q=qw+li]
            f32x4 s[4];
            __builtin_amdgcn_s_setprio(1);
            #pragma unroll
            for (int c = 0; c < 4; ++c) {
                f32x4 acc = {};
                #pragma unroll
                for (int eh = 0; eh < 2; ++eh) {
                    bf16x8 kb = *(const bf16x8*)&Klin[cur][(c * 16 + li) * 64 + (((eh * 4 + g) ^ (li & 7)) * 8)];
                    acc = __builtin_amdgcn_mfma_f32_16x16x32_bf16(kb, qa[eh], acc, 0, 0, 0);
                }
                s[c] = acc;
            }
            __builtin_amdgcn_s_setprio(0);
            const int lg = qw + li;
            if (kv0 + 63 > qw) {
                #pragma unroll
                for (int c = 0; c < 4; ++c) {
                    const int kvb = kv0 + ((c >> 1) << 5) + (g << 3) + ((c & 1) << 2);
                    #pragma unroll
                    for (int r = 0; r < 4; ++r)
                        s[c][r] = (kvb + r <= lg) ? fmaf(bc[c][r], SC, s[c][r]) : -INFINITY;
                }
            } else {
                #pragma unroll
                for (int c = 0; c < 4; ++c)
                    #pragma unroll
                    for (int r = 0; r < 4; ++r)
                        s[c][r] = fmaf(bc[c][r], SC, s[c][r]);
            }
            float pm = fmaxf(
                fmaxf(fmaxf(fmaxf(s[0][0],s[0][1]),fmaxf(s[0][2],s[0][3])),
                      fmaxf(fmaxf(s[1][0],s[1][1]),fmaxf(s[1][2],s[1][3]))),
                fmaxf(fmaxf(fmaxf(s[2][0],s[2][1]),fmaxf(s[2][2],s[2][3])),
                      fmaxf(fmaxf(s[3][0],s[3][1]),fmaxf(s[3][2],s[3][3]))));
            pm = fmaxf(pm, __shfl_xor(pm, 16, 64));
            pm = fmaxf(pm, __shfl_xor(pm, 32, 64));
            if (!__all(pm <= m_run + 8.0f)) {     // defer-max
                const float mn = fmaxf(m_run, pm);
                const float corr = exp2f(m_run - mn);
                m_run = mn; l_run *= corr;
                #pragma unroll
                for (int j = 0; j < 4; ++j) {
                    const float cj = bpermf(g * 20 + j, corr);
                    o[0][j] *= cj; o[1][j] *= cj; o[2][j] *= cj; o[3][j] *= cj;
                }
            }
            #pragma unroll
            for (int c = 0; c < 4; ++c)
                #pragma unroll
                for (int r = 0; r < 4; ++r)
                    s[c][r] = exp2f(s[c][r] - m_run);
            float rs = ((s[0][0]+s[0][1])+(s[0][2]+s[0][3]))
                     + ((s[1][0]+s[1][1])+(s[1][2]+s[1][3]))
                     + ((s[2][0]+s[2][1])+(s[2][2]+s[2][3]))
                     + ((s[3][0]+s[3][1])+(s[3][2]+s[3][3]));
            rs += __shfl_xor(rs, 16, 64);
            rs += __shfl_xor(rs, 32, 64);
            l_run += rs;
            u32x4 pw0, pw1;
            pw0[0] = cvtpk(s[0][0], s[0][1]); pw0[1] = cvtpk(s[0][2], s[0][3]);
            pw0[2] = cvtpk(s[1][0], s[1][1]); pw0[3] = cvtpk(s[1][2], s[1][3]);
            pw1[0] = cvtpk(s[2][0], s[2][1]); pw1[1] = cvtpk(s[2][2], s[2][3]);
            pw1[2] = cvtpk(s[3][0], s[3][1]); pw1[3] = cvtpk(s[3][2], s[3][3]);
            const bf16x8 pa0 = __builtin_bit_cast(bf16x8, pw0);
            const bf16x8 pa1 = __builtin_bit_cast(bf16x8, pw1);
            __builtin_amdgcn_s_setprio(1);
            #pragma unroll
            for (int dt = 0; dt < 4; ++dt) {
                const int d = dt * 16 + li;
                const int sd = (d ^ (d >> 3)) & 7;
                bf16x8 v0 = *(const bf16x8*)&Vlin[cur][d * 64 + ((g ^ sd) * 8)];
                bf16x8 v1 = *(const bf16x8*)&Vlin[cur][d * 64 + (((4 + g) ^ sd) * 8)];
                o[dt] = __builtin_amdgcn_mfma_f32_16x16x32_bf16(pa0, v0, o[dt], 0, 0, 0);
                o[dt] = __builtin_amdgcn_mfma_f32_16x16x32_bf16(pa1, v1, o[dt], 0, 0, 0);
            }
            __builtin_amdgcn_s_setprio(0);
        }

        if (more) {
            __syncthreads();    // drains gloads for t+1, separates buffer reuse
            #pragma unroll
            for (int c = 0; c < 4; ++c) bc[c] = bn[c];
        }
    }

    if (WRITE_WS) {
        #pragma unroll
        for (int j = 0; j < 4; ++j) {
            const int lp = qw + g * 4 + j - 1024;   // half-L index (l>=1536 here)
            float* op = OutOrO + (((size_t)(b * 1024 + lp)) * NH + h) * ND + li;
            op[0]  = o[0][j];
            op[16] = o[1][j];
            op[32] = o[2][j];
            op[48] = o[3][j];
        }
        if (g == 0) {
            const size_t rh = ((size_t)(b * 1024 + qw + li - 1024)) * NH + h;
            Mp[rh] = m_run;
            Lp[rh] = l_run;
        }
    } else {
        #pragma unroll
        for (int j = 0; j < 4; ++j) {
            const float lj = bpermf(g * 20 + j, l_run);
            const float inv = 1.0f / lj;
            const int lgq = qw + g * 4 + j;
            float* op = OutOrO + (((size_t)(b * NL + lgq)) * NH + h) * ND + li;
            op[0]  = o[0][j] * inv;
            op[16] = o[1][j] * inv;
            op[32] = o[2][j] * inv;
            op[48] = o[3][j] * inv;
        }
    }
}

// ---- split kernel: 1280 blocks = 40 segs (heavy-first) x 32 bh ----
// k=0..7:   qc=23-k, unsplit (24..17 tiles)
// k=8..15:  qc=31-(k-8),  s=0, tiles [0,16)
// k=16..23: qc=31-(k-16), s=1, tiles [16,qc+1) (16..9 tiles)
// k=24..39: qc=15-(k-24), unsplit (16..1 tiles)
__global__ __launch_bounds__(256)
void fa_part(const float* __restrict__ Q, const float* __restrict__ Bias,
             float* __restrict__ Ws, float* __restrict__ Out)
{
    __shared__ __bf16 Klin[2][4096];
    __shared__ __bf16 Vlin[2][4096];

    const int id = blockIdx.x;
    const int bh = id & 31, k = id >> 5;
    const int b  = bh >> 3, h = bh & 7;
    int qc, s;
    if (k < 8)       { qc = 23 - k;        s = 0; }
    else if (k < 16) { qc = 31 - (k - 8);  s = 0; }
    else if (k < 24) { qc = 31 - (k - 16); s = 1; }
    else             { qc = 15 - (k - 24); s = 0; }
    const bool split = (qc >= 24);
    const int qb = qc << 6;
    const int t0 = (split && s) ? 16 : 0;
    const int t1 = split ? (s ? qc + 1 : 16) : (qc + 1);

    const u16* Kbf = (const u16*)(Ws + KBF_F);
    const u16* Vt  = (const u16*)(Ws + VT_F);
    if (split) {
        float* Op = Ws + OP_F + (size_t)s * 2097152;
        float* Mp = Ws + M_F + (size_t)s * 32768;
        float* Lp = Ws + L_F + (size_t)s * 32768;
        fa_core<true>(Q, Kbf, Vt, Bias, Op, Mp, Lp, b, h, qb, t0, t1, Klin, Vlin);
    } else {
        fa_core<false>(Q, Kbf, Vt, Bias, Out, nullptr, nullptr, b, h, qb, t0, t1, Klin, Vlin);
    }
}

// ---- merge kernel: rows l in [1536,2048) only (qc>=24 => exactly 2 segments) ----
__global__ __launch_bounds__(256)
void fa_merge(const float* __restrict__ Ws, float* __restrict__ Out)
{
    const int gid  = blockIdx.x * 256 + threadIdx.x;   // 0 .. 262,143
    const int base4 = gid << 2;
    const int d0   = base4 & 63;
    const int rhh  = base4 >> 6;          // (b*512 + lq)*8 + h, lq in [0,512)
    const int h    = rhh & 7;
    const int t    = rhh >> 3;
    const int lq   = t & 511, b = t >> 9;
    const int lp   = 512 + lq;            // ws half-L row index
    const size_t rh   = ((size_t)(b * 1024 + lp)) * NH + h;
    const size_t obase = rh * 64 + d0;
    const float m1 = Ws[M_F + rh],         l1 = Ws[L_F + rh];
    const float m2 = Ws[M_F + 32768 + rh], l2 = Ws[L_F + 32768 + rh];
    const float mm = fmaxf(m1, m2);
    const float c1 = exp2f(m1 - mm), c2 = exp2f(m2 - mm);
    const float inv = 1.0f / (c1 * l1 + c2 * l2);
    const f32x4 o1 = *(const f32x4*)(Ws + OP_F + obase);
    const f32x4 o2 = *(const f32x4*)(Ws + OP_F + 2097152 + obase);
    f32x4 r;
    #pragma unroll
    for (int e = 0; e < 4; ++e) r[e] = (c1 * o1[e] + c2 * o2[e]) * inv;
    float* op = Out + (((size_t)(b * NL + 1024 + lp)) * NH + h) * ND + d0;
    *(f32x4*)op = r;
}

// ---- fallback (ws only fits Kbf+Vt): single kernel, full chunk ranges ----
__global__ __launch_bounds__(256)
void fa_single(const float* __restrict__ Q, const float* __restrict__ Bias,
               float* __restrict__ Ws, float* __restrict__ Out)
{
    __shared__ __bf16 Klin[2][4096];
    __shared__ __bf16 Vlin[2][4096];
    const int id = blockIdx.x;
    const int bh = id & 31, qc = 31 - (id >> 5);
    const int b  = bh >> 3, h = bh & 7;
    const u16* Kbf = (const u16*)(Ws + KBF_F);
    const u16* Vt  = (const u16*)(Ws + VT_F);
    fa_core<false>(Q, Kbf, Vt, Bias, Out, nullptr, nullptr, b, h, qc << 6, 0, qc + 1, Klin, Vlin);
}

extern "C" void kernel_launch(void* const* d_in, const int* in_sizes, int n_in,
                              void* d_out, int out_size, void* d_ws, size_t ws_size,
                              hipStream_t stream)
{
    const float* Q    = (const float*)d_in[0];
    const float* K    = (const float*)d_in[1];
    const float* V    = (const float*)d_in[2];
    const float* Bias = (const float*)d_in[3];
    float* Out = (float*)d_out;
    float* Ws  = (float*)d_ws;

    prep<<<dim3(3072), dim3(256), 0, stream>>>(K, V, (u16*)(Ws + KBF_F), (u16*)(Ws + VT_F));

    if (ws_size >= (size_t)WS_NEED_F * sizeof(float)) {
        fa_part <<<dim3(1280), dim3(256), 0, stream>>>(Q, Bias, Ws, Out);
        fa_merge<<<dim3(1024), dim3(256), 0, stream>>>(Ws, Out);
    } else {
        fa_single<<<dim3(1024), dim3(256), 0, stream>>>(Q, Bias, Ws, Out);
    }
}

// Round 25
// 83.957 us; speedup vs baseline: 1.2620x; 1.0139x over previous
//
#include <hip/hip_runtime.h>
#include <hip/hip_bf16.h>
#include <math.h>

// CausalFullAttention: out[b,l,h,d] = softmax_s( 0.125*(q.k + bias[l,s]), s<=l ) @ V
// B=4 L=S=2048 H=8 E=D=64, fp32 in/out, bf16 MFMA compute.
// R24: R23 + deferred l-reduction (per-lane partial, cross-lane shuffles moved to
//      epilogue; removes 2 shfl from every tile-step's dependency chain) and hoisted
//      bias addressing. Split policy / core / prep / merge unchanged from R23 best.

typedef __bf16 bf16x8 __attribute__((ext_vector_type(8)));
typedef float  f32x4  __attribute__((ext_vector_type(4)));
typedef unsigned int u32;
typedef unsigned short u16;
typedef u32 u32x4 __attribute__((ext_vector_type(4)));

#define NB 4
#define NL 2048
#define NS 2048
#define NH 8
#define NE 64
#define ND 64

// ws layout (floats)
#define KBF_F 0
#define VT_F  2097152
#define OP_F  4194304
#define M_F   8388608
#define L_F   8454144
#define WS_NEED_F 8519680          // 34,078,720 bytes

typedef __attribute__((address_space(3))) u32 lds_u32;
typedef __attribute__((address_space(1))) const u32 glb_u32;
__device__ __forceinline__ void gload16(const void* g, void* l) {
    __builtin_amdgcn_global_load_lds((glb_u32*)g, (lds_u32*)l, 16, 0, 0);
}

__device__ __forceinline__ u32 cvtpk(float lo, float hi) {
    u32 r;
    asm("v_cvt_pk_bf16_f32 %0, %1, %2" : "=v"(r) : "v"(lo), "v"(hi));
    return r;
}
__device__ __forceinline__ float bpermf(int srclane, float v) {
    return __uint_as_float((u32)__builtin_amdgcn_ds_bpermute(srclane << 2, (int)__float_as_uint(v)));
}
__device__ __forceinline__ bf16x8 cvt8s(f32x4 a, f32x4 b, float sc) {
    bf16x8 r;
    r[0]=(__bf16)(a[0]*sc); r[1]=(__bf16)(a[1]*sc); r[2]=(__bf16)(a[2]*sc); r[3]=(__bf16)(a[3]*sc);
    r[4]=(__bf16)(b[0]*sc); r[5]=(__bf16)(b[1]*sc); r[6]=(__bf16)(b[2]*sc); r[7]=(__bf16)(b[3]*sc);
    return r;
}
__device__ __forceinline__ bf16x8 cvt8(f32x4 a, f32x4 b) {
    bf16x8 r;
    r[0]=(__bf16)a[0]; r[1]=(__bf16)a[1]; r[2]=(__bf16)a[2]; r[3]=(__bf16)a[3];
    r[4]=(__bf16)b[0]; r[5]=(__bf16)b[1]; r[6]=(__bf16)b[2]; r[7]=(__bf16)b[3];
    return r;
}

// -------- fused pre-pass: blocks [0,2048) convert K; [2048,3072) transpose V -----
__global__ __launch_bounds__(256)
void prep(const float* __restrict__ K, const float* __restrict__ V,
          u16* __restrict__ Kbf, u16* __restrict__ Vt)
{
    __shared__ __bf16 T[64][72];
    const int bid = blockIdx.x;
    const int t   = threadIdx.x;
    if (bid < 2048) {
        const int i = (bid * 256 + t) * 8;
        f32x4 a = *(const f32x4*)(K + i);
        f32x4 b = *(const f32x4*)(K + i + 4);
        *(bf16x8*)(Kbf + i) = cvt8(a, b);
    } else {
        const int id = bid - 2048;
        const int bh = id >> 5, sblk = (id & 31) << 6;
        const int b = bh >> 3, h = bh & 7;
        {
            const int sl = t >> 2, d0 = (t & 3) << 4;
            const float* vp = V + (((size_t)(b * NS + sblk + sl)) * NH + h) * ND + d0;
            f32x4 a0 = ((const f32x4*)vp)[0], a1 = ((const f32x4*)vp)[1];
            f32x4 a2 = ((const f32x4*)vp)[2], a3 = ((const f32x4*)vp)[3];
            *(bf16x8*)&T[sl][d0]     = cvt8(a0, a1);
            *(bf16x8*)&T[sl][d0 + 8] = cvt8(a2, a3);
        }
        __syncthreads();
        {
            const int dl = t >> 2, s0 = (t & 3) << 4;
            bf16x8 o0, o1;
            #pragma unroll
            for (int k = 0; k < 8; ++k) { o0[k] = T[s0 + k][dl]; o1[k] = T[s0 + 8 + k][dl]; }
            u16* op = Vt + (((size_t)(b * NH + h)) * ND + dl) * NS + sblk + s0;
            *(bf16x8*)op       = o0;
            *(bf16x8*)(op + 8) = o1;
        }
    }
}

// ---- core: 256 threads, 4 waves x 16 q-rows, tiles [t0,t1); gload_lds staging ----
template<bool WRITE_WS>
__device__ __forceinline__ void fa_core(const float* __restrict__ Q,
                                        const u16* __restrict__ Kbf,
                                        const u16* __restrict__ Vt,
                                        const float* __restrict__ Bias,
                                        float* __restrict__ OutOrO,
                                        float* __restrict__ Mp, float* __restrict__ Lp,
                                        int b, int h, int qb, int t0, int t1,
                                        __bf16 (*Klin)[4096], __bf16 (*Vlin)[4096])
{
    const int tid  = threadIdx.x;
    const int w    = tid >> 6, lane = tid & 63;
    const int g    = lane >> 4, li = lane & 15;
    const int qw   = qb + (w << 4);

    const float SC = 0.125f * 1.44269504088896340736f;

    bf16x8 qa[2];
    {
        const float* qp = Q + (((size_t)(b * NL + qw + li)) * NH + h) * NE;
        #pragma unroll
        for (int eh = 0; eh < 2; ++eh) {
            const int e0 = eh * 32 + g * 8;
            f32x4 f0 = *(const f32x4*)(qp + e0);
            f32x4 f1 = *(const f32x4*)(qp + e0 + 4);
            qa[eh] = cvt8s(f0, f1, SC);
        }
    }

    f32x4 o[4] = {};
    float m_run = -INFINITY, l_part = 0.0f;   // l: per-lane partial, reduced in epilogue

    const int nt = t1 - t0;

    // per-lane gload source geometry (2 K issues + 2 V issues per thread)
    const int ob0 = w * 2048 + lane * 16;            // LDS byte offset, issue 0
    const int r0  = ob0 >> 7,          j0 = (ob0 >> 4) & 7;
    const int r1  = (ob0 + 1024) >> 7, j1 = ((ob0 + 1024) >> 4) & 7;
    // rho^-1: kv2=r4, kv4:3=r3:2, rest pass-through
    const int kv0i = (r0 & 0x23) | ((r0 & 0x10) >> 2) | ((r0 & 0x0C) << 1);
    const int kv1i = (r1 & 0x23) | ((r1 & 0x10) >> 2) | ((r1 & 0x0C) << 1);
    const u16* kgp0 = Kbf + ((size_t)(b * NS + kv0i) * NH + h) * NE + (j0 ^ (r0 & 7)) * 8;
    const u16* kgp1 = Kbf + ((size_t)(b * NS + kv1i) * NH + h) * NE + (j1 ^ (r1 & 7)) * 8;
    const int sd0 = (r0 ^ (r0 >> 3)) & 7, sd1 = (r1 ^ (r1 >> 3)) & 7;
    const u16* vgp0 = Vt + ((size_t)(b * NH + h) * ND + r0) * NS + (j0 ^ sd0) * 8;
    const u16* vgp1 = Vt + ((size_t)(b * NH + h) * ND + r1) * NS + (j1 ^ sd1) * 8;

    // hoisted bias addressing: two fixed row pointers, stride 64 floats per tile
    const float* bpA = Bias + (size_t)(qw + li) * NS + g * 8 + (t0 << 6);
    const float* bpB = bpA + 32;

    f32x4 bc[4], bn[4];

    auto stage = [&](int buf, int T) {
        const size_t kq = (size_t)(T << 6) * (NH * NE);
        const int    vq = T << 6;
        gload16(kgp0 + kq, &Klin[buf][w * 1024]);
        gload16(kgp1 + kq, &Klin[buf][w * 1024 + 512]);
        gload16(vgp0 + vq, &Vlin[buf][w * 1024]);
        gload16(vgp1 + vq, &Vlin[buf][w * 1024 + 512]);
    };
    auto load_bias = [&](f32x4 (&bx)[4], int i) {
        const int off = i << 6;
        bx[0] = *(const f32x4*)(bpA + off);
        bx[1] = *(const f32x4*)(bpA + off + 4);
        bx[2] = *(const f32x4*)(bpB + off);
        bx[3] = *(const f32x4*)(bpB + off + 4);
    };

    // prologue
    stage(0, t0);
    load_bias(bc, 0);
    __syncthreads();

    for (int i = 0; i < nt; ++i) {
        const int t = t0 + i;
        const int cur = i & 1;
        const bool more = (i + 1 < nt);

        if (more) { stage(cur ^ 1, t + 1); load_bias(bn, i + 1); }

        const int kv0 = t << 6;
        if (kv0 <= qw + 15) {
            // swapped QK^T: s[c][r] = S[kv=kv0+32(c>>1)+8g+4(c&1)+r][q=qw+li]
            f32x4 s[4];
            __builtin_amdgcn_s_setprio(1);
            #pragma unroll
            for (int c = 0; c < 4; ++c) {
                f32x4 acc = {};
                #pragma unroll
                for (int eh = 0; eh < 2; ++eh) {
                    bf16x8 kb = *(const bf16x8*)&Klin[cur][(c * 16 + li) * 64 + (((eh * 4 + g) ^ (li & 7)) * 8)];
                    acc = __builtin_amdgcn_mfma_f32_16x16x32_bf16(kb, qa[eh], acc, 0, 0, 0);
                }
                s[c] = acc;
            }
            __builtin_amdgcn_s_setprio(0);
            const int lg = qw + li;
            if (kv0 + 63 > qw) {
                #pragma unroll
                for (int c = 0; c < 4; ++c) {
                    const int kvb = kv0 + ((c >> 1) << 5) + (g << 3) + ((c & 1) << 2);
                    #pragma unroll
                    for (int r = 0; r < 4; ++r)
                        s[c][r] = (kvb + r <= lg) ? fmaf(bc[c][r], SC, s[c][r]) : -INFINITY;
                }
            } else {
                #pragma unroll
                for (int c = 0; c < 4; ++c)
                    #pragma unroll
                    for (int r = 0; r < 4; ++r)
                        s[c][r] = fmaf(bc[c][r], SC, s[c][r]);
            }
            float pm = fmaxf(
                fmaxf(fmaxf(fmaxf(s[0][0],s[0][1]),fmaxf(s[0][2],s[0][3])),
                      fmaxf(fmaxf(s[1][0],s[1][1]),fmaxf(s[1][2],s[1][3]))),
                fmaxf(fmaxf(fmaxf(s[2][0],s[2][1]),fmaxf(s[2][2],s[2][3])),
                      fmaxf(fmaxf(s[3][0],s[3][1]),fmaxf(s[3][2],s[3][3]))));
            pm = fmaxf(pm, __shfl_xor(pm, 16, 64));
            pm = fmaxf(pm, __shfl_xor(pm, 32, 64));
            if (!__all(pm <= m_run + 8.0f)) {     // defer-max (T13)
                const float mn = fmaxf(m_run, pm);
                const float corr = exp2f(m_run - mn);
                m_run = mn; l_part *= corr;       // per-lane partial scales uniformly
                #pragma unroll
                for (int j = 0; j < 4; ++j) {
                    const float cj = bpermf(g * 20 + j, corr);
                    o[0][j] *= cj; o[1][j] *= cj; o[2][j] *= cj; o[3][j] *= cj;
                }
            }
            #pragma unroll
            for (int c = 0; c < 4; ++c)
                #pragma unroll
                for (int r = 0; r < 4; ++r)
                    s[c][r] = exp2f(s[c][r] - m_run);
            // deferred l: per-lane in-lane sum only (no cross-lane shuffles in loop)
            l_part += (((s[0][0]+s[0][1])+(s[0][2]+s[0][3]))
                     + ((s[1][0]+s[1][1])+(s[1][2]+s[1][3])))
                    + (((s[2][0]+s[2][1])+(s[2][2]+s[2][3]))
                     + ((s[3][0]+s[3][1])+(s[3][2]+s[3][3])));
            u32x4 pw0, pw1;
            pw0[0] = cvtpk(s[0][0], s[0][1]); pw0[1] = cvtpk(s[0][2], s[0][3]);
            pw0[2] = cvtpk(s[1][0], s[1][1]); pw0[3] = cvtpk(s[1][2], s[1][3]);
            pw1[0] = cvtpk(s[2][0], s[2][1]); pw1[1] = cvtpk(s[2][2], s[2][3]);
            pw1[2] = cvtpk(s[3][0], s[3][1]); pw1[3] = cvtpk(s[3][2], s[3][3]);
            const bf16x8 pa0 = __builtin_bit_cast(bf16x8, pw0);
            const bf16x8 pa1 = __builtin_bit_cast(bf16x8, pw1);
            __builtin_amdgcn_s_setprio(1);
            #pragma unroll
            for (int dt = 0; dt < 4; ++dt) {
                const int d = dt * 16 + li;
                const int sd = (d ^ (d >> 3)) & 7;
                bf16x8 v0 = *(const bf16x8*)&Vlin[cur][d * 64 + ((g ^ sd) * 8)];
                bf16x8 v1 = *(const bf16x8*)&Vlin[cur][d * 64 + (((4 + g) ^ sd) * 8)];
                o[dt] = __builtin_amdgcn_mfma_f32_16x16x32_bf16(pa0, v0, o[dt], 0, 0, 0);
                o[dt] = __builtin_amdgcn_mfma_f32_16x16x32_bf16(pa1, v1, o[dt], 0, 0, 0);
            }
            __builtin_amdgcn_s_setprio(0);
        }

        if (more) {
            __syncthreads();    // drains gloads for t+1, separates buffer reuse
            #pragma unroll
            for (int c = 0; c < 4; ++c) bc[c] = bn[c];
        }
    }

    // epilogue: finish the l reduction once
    float l_run = l_part;
    l_run += __shfl_xor(l_run, 16, 64);
    l_run += __shfl_xor(l_run, 32, 64);

    if (WRITE_WS) {
        #pragma unroll
        for (int j = 0; j < 4; ++j) {
            const int lp = qw + g * 4 + j - 1024;   // half-L index (l>=1536 here)
            float* op = OutOrO + (((size_t)(b * 1024 + lp)) * NH + h) * ND + li;
            op[0]  = o[0][j];
            op[16] = o[1][j];
            op[32] = o[2][j];
            op[48] = o[3][j];
        }
        if (g == 0) {
            const size_t rh = ((size_t)(b * 1024 + qw + li - 1024)) * NH + h;
            Mp[rh] = m_run;
            Lp[rh] = l_run;
        }
    } else {
        #pragma unroll
        for (int j = 0; j < 4; ++j) {
            const float lj = bpermf(g * 20 + j, l_run);
            const float inv = 1.0f / lj;
            const int lgq = qw + g * 4 + j;
            float* op = OutOrO + (((size_t)(b * NL + lgq)) * NH + h) * ND + li;
            op[0]  = o[0][j] * inv;
            op[16] = o[1][j] * inv;
            op[32] = o[2][j] * inv;
            op[48] = o[3][j] * inv;
        }
    }
}

// ---- split kernel: 1280 blocks = 40 segs (heavy-first) x 32 bh ----
__global__ __launch_bounds__(256)
void fa_part(const float* __restrict__ Q, const float* __restrict__ Bias,
             float* __restrict__ Ws, float* __restrict__ Out)
{
    __shared__ __bf16 Klin[2][4096];
    __shared__ __bf16 Vlin[2][4096];

    const int id = blockIdx.x;
    const int bh = id & 31, k = id >> 5;
    const int b  = bh >> 3, h = bh & 7;
    int qc, s;
    if (k < 8)       { qc = 23 - k;        s = 0; }
    else if (k < 16) { qc = 31 - (k - 8);  s = 0; }
    else if (k < 24) { qc = 31 - (k - 16); s = 1; }
    else             { qc = 15 - (k - 24); s = 0; }
    const bool split = (qc >= 24);
    const int qb = qc << 6;
    const int t0 = (split && s) ? 16 : 0;
    const int t1 = split ? (s ? qc + 1 : 16) : (qc + 1);

    const u16* Kbf = (const u16*)(Ws + KBF_F);
    const u16* Vt  = (const u16*)(Ws + VT_F);
    if (split) {
        float* Op = Ws + OP_F + (size_t)s * 2097152;
        float* Mp = Ws + M_F + (size_t)s * 32768;
        float* Lp = Ws + L_F + (size_t)s * 32768;
        fa_core<true>(Q, Kbf, Vt, Bias, Op, Mp, Lp, b, h, qb, t0, t1, Klin, Vlin);
    } else {
        fa_core<false>(Q, Kbf, Vt, Bias, Out, nullptr, nullptr, b, h, qb, t0, t1, Klin, Vlin);
    }
}

// ---- merge kernel: rows l in [1536,2048) only (qc>=24 => exactly 2 segments) ----
__global__ __launch_bounds__(256)
void fa_merge(const float* __restrict__ Ws, float* __restrict__ Out)
{
    const int gid  = blockIdx.x * 256 + threadIdx.x;   // 0 .. 262,143
    const int base4 = gid << 2;
    const int d0   = base4 & 63;
    const int rhh  = base4 >> 6;          // (b*512 + lq)*8 + h, lq in [0,512)
    const int h    = rhh & 7;
    const int t    = rhh >> 3;
    const int lq   = t & 511, b = t >> 9;
    const int lp   = 512 + lq;            // ws half-L row index
    const size_t rh   = ((size_t)(b * 1024 + lp)) * NH + h;
    const size_t obase = rh * 64 + d0;
    const float m1 = Ws[M_F + rh],         l1 = Ws[L_F + rh];
    const float m2 = Ws[M_F + 32768 + rh], l2 = Ws[L_F + 32768 + rh];
    const float mm = fmaxf(m1, m2);
    const float c1 = exp2f(m1 - mm), c2 = exp2f(m2 - mm);
    const float inv = 1.0f / (c1 * l1 + c2 * l2);
    const f32x4 o1 = *(const f32x4*)(Ws + OP_F + obase);
    const f32x4 o2 = *(const f32x4*)(Ws + OP_F + 2097152 + obase);
    f32x4 r;
    #pragma unroll
    for (int e = 0; e < 4; ++e) r[e] = (c1 * o1[e] + c2 * o2[e]) * inv;
    float* op = Out + (((size_t)(b * NL + 1024 + lp)) * NH + h) * ND + d0;
    *(f32x4*)op = r;
}

// ---- fallback (ws only fits Kbf+Vt): single kernel, full chunk ranges ----
__global__ __launch_bounds__(256)
void fa_single(const float* __restrict__ Q, const float* __restrict__ Bias,
               float* __restrict__ Ws, float* __restrict__ Out)
{
    __shared__ __bf16 Klin[2][4096];
    __shared__ __bf16 Vlin[2][4096];
    const int id = blockIdx.x;
    const int bh = id & 31, qc = 31 - (id >> 5);
    const int b  = bh >> 3, h = bh & 7;
    const u16* Kbf = (const u16*)(Ws + KBF_F);
    const u16* Vt  = (const u16*)(Ws + VT_F);
    fa_core<false>(Q, Kbf, Vt, Bias, Out, nullptr, nullptr, b, h, qc << 6, 0, qc + 1, Klin, Vlin);
}

extern "C" void kernel_launch(void* const* d_in, const int* in_sizes, int n_in,
                              void* d_out, int out_size, void* d_ws, size_t ws_size,
                              hipStream_t stream)
{
    const float* Q    = (const float*)d_in[0];
    const float* K    = (const float*)d_in[1];
    const float* V    = (const float*)d_in[2];
    const float* Bias = (const float*)d_in[3];
    float* Out = (float*)d_out;
    float* Ws  = (float*)d_ws;

    prep<<<dim3(3072), dim3(256), 0, stream>>>(K, V, (u16*)(Ws + KBF_F), (u16*)(Ws + VT_F));

    if (ws_size >= (size_t)WS_NEED_F * sizeof(float)) {
        fa_part <<<dim3(1280), dim3(256), 0, stream>>>(Q, Bias, Ws, Out);
        fa_merge<<<dim3(1024), dim3(256), 0, stream>>>(Ws, Out);
    } else {
        fa_single<<<dim3(1024), dim3(256), 0, stream>>>(Q, Bias, Ws, Out);
    }
}